// Round 1
// baseline (85.913 us; speedup 1.0000x reference)
//
#include <hip/hip_runtime.h>
#include <stdint.h>

// Problem: B=32, P=16, E=50000, H=128
#define E_DIM 50000
#define EP    50048          // E padded to multiple of 64
#define HD    128
#define BD    32
#define PD    16
#define MD    512            // B*P
#define KCHUNK 768           // 12 stages of BK=64
#define NKC   66             // ceil(EP/KCHUNK); last chunk = 128 (2 stages)
#define EPSF  1e-5f

typedef short short8 __attribute__((ext_vector_type(8)));   // 8 bf16 (4 VGPRs)
typedef float f32x4  __attribute__((ext_vector_type(4)));

__device__ __forceinline__ uint16_t f2bf(float f) {
  uint32_t u = __float_as_uint(f);
  u += 0x7FFFu + ((u >> 16) & 1u);           // round-to-nearest-even
  return (uint16_t)(u >> 16);
}

// ---------------------------------------------------------------------------
// Kernel 1: emb [E][H] fp32 -> embT [H][EP] bf16 (transposed, row0 zeroed,
// e >= E_DIM zero-padded). LDS tile transpose with XOR swizzle.
// ---------------------------------------------------------------------------
__global__ __launch_bounds__(256) void k_embT(const float* __restrict__ emb,
                                              uint16_t* __restrict__ embT) {
  __shared__ __align__(16) uint16_t lds[HD * 64];   // [h][e_local], swizzled
  const int t  = threadIdx.x;
  const int e0 = blockIdx.x * 64;

#pragma unroll
  for (int pass = 0; pass < 8; ++pass) {
    const int el = pass * 8 + (t >> 5);       // 0..63
    const int h  = (t & 31) * 4;              // 0..124
    const int eg = e0 + el;
    float4 v = {0.f, 0.f, 0.f, 0.f};
    if (eg < E_DIM && eg != 0)                // padding_idx=0 -> zero row
      v = *(const float4*)(emb + (size_t)eg * HD + h);
    const uint16_t q0 = f2bf(v.x), q1 = f2bf(v.y), q2 = f2bf(v.z), q3 = f2bf(v.w);
    lds[(h + 0) * 64 + (el ^ (((h + 0) & 7) << 3))] = q0;
    lds[(h + 1) * 64 + (el ^ (((h + 1) & 7) << 3))] = q1;
    lds[(h + 2) * 64 + (el ^ (((h + 2) & 7) << 3))] = q2;
    lds[(h + 3) * 64 + (el ^ (((h + 3) & 7) << 3))] = q3;
  }
  __syncthreads();
#pragma unroll
  for (int pass = 0; pass < 8; ++pass) {
    const int hr  = pass * 16 + (t >> 4);     // 0..127
    const int el4 = (t & 15) * 4;             // 0..60
    uint2 d = *(const uint2*)(lds + hr * 64 + (el4 ^ ((hr & 7) << 3)));
    *(uint2*)(embT + (size_t)hr * EP + e0 + el4) = d;
  }
}

// ---------------------------------------------------------------------------
// Kernel 2: partial GEMM. C_part[kc][mt][64][128] = mask_tile * embT_chunk
// A (mask) converted int32 -> bf16 on the fly, staged in swizzled LDS.
// B fragments loaded per-lane directly from embT (contiguous 16B in [h][e]).
// Also emits per-chunk per-row mask counts.
// ---------------------------------------------------------------------------
__global__ __launch_bounds__(256) void k_gemm(const int* __restrict__ inp,
                                              const uint16_t* __restrict__ embT,
                                              float* __restrict__ part,
                                              float* __restrict__ cntp) {
  __shared__ __align__(16) uint16_t ldsA[64 * 64];   // [row][k] bf16, swizzled
  __shared__ int ldsCnt[64];

  const int t  = threadIdx.x;
  const int kc = blockIdx.x >> 3;
  const int mt = blockIdx.x & 7;
  const int e_base   = kc * KCHUNK;
  const int row_base = mt * 64;
  const int nst = min(12, (EP - e_base) >> 6);

  if (t < 64) ldsCnt[t] = 0;

  int cnt4[4] = {0, 0, 0, 0};
  f32x4 acc[2][4];
#pragma unroll
  for (int mf = 0; mf < 2; ++mf)
#pragma unroll
    for (int hf = 0; hf < 4; ++hf) acc[mf][hf] = (f32x4){0.f, 0.f, 0.f, 0.f};

  const int lane = t & 63;
  const int wid  = t >> 6;
  const int wr   = wid >> 1;   // wave row (0..1) -> 32 rows each
  const int wc   = wid & 1;    // wave col (0..1) -> 64 cols each

  for (int s = 0; s < nst; ++s) {
    const int e0 = e_base + s * 64;
    // ---- stage A tile: 64 rows x 64 k, int32 -> bf16 {0,1} ----
#pragma unroll
    for (int p = 0; p < 4; ++p) {
      const int rl  = (t >> 4) + p * 16;        // 0..63
      const int col = (t & 15) * 4;             // 0..60
      const int eg  = e0 + col;
      int4 v = {0, 0, 0, 0};
      if (eg + 3 < E_DIM)                        // E_DIM % 4 == 0: all-or-none
        v = *(const int4*)(inp + (size_t)(row_base + rl) * E_DIM + eg);
      const uint32_t m0 = (v.x == 1), m1 = (v.y == 1), m2 = (v.z == 1), m3 = (v.w == 1);
      cnt4[p] += (int)(m0 + m1 + m2 + m3);
      const uint32_t lo = (m0 ? 0x3F80u : 0u) | ((m1 ? 0x3F80u : 0u) << 16);
      const uint32_t hi = (m2 ? 0x3F80u : 0u) | ((m3 ? 0x3F80u : 0u) << 16);
      const int byte = (col * 2) ^ ((rl & 7) << 4);   // XOR swizzle
      *(uint2*)((char*)ldsA + rl * 128 + byte) = (uint2){lo, hi};
    }
    __syncthreads();
    // ---- MFMA over BK=64 (two k-steps of 32) ----
#pragma unroll
    for (int kk = 0; kk < 64; kk += 32) {
      short8 a[2], b[4];
#pragma unroll
      for (int mf = 0; mf < 2; ++mf) {
        const int row = wr * 32 + mf * 16 + (lane & 15);
        const int kb  = (kk + ((lane >> 4) << 3)) * 2;
        a[mf] = *(const short8*)((const char*)ldsA + row * 128 + (kb ^ ((row & 7) << 4)));
      }
#pragma unroll
      for (int hf = 0; hf < 4; ++hf) {
        const int h  = wc * 64 + hf * 16 + (lane & 15);
        const int eg = e0 + kk + ((lane >> 4) << 3);
        b[hf] = *(const short8*)(embT + (size_t)h * EP + eg);
      }
#pragma unroll
      for (int mf = 0; mf < 2; ++mf)
#pragma unroll
        for (int hf = 0; hf < 4; ++hf)
          acc[mf][hf] = __builtin_amdgcn_mfma_f32_16x16x32_bf16(
              a[mf], b[hf], acc[mf][hf], 0, 0, 0);
    }
    __syncthreads();
  }

  // ---- epilogue: partial tile + counts ----
  float* pt = part + (size_t)(kc * 8 + mt) * (64 * 128);
#pragma unroll
  for (int mf = 0; mf < 2; ++mf)
#pragma unroll
    for (int hf = 0; hf < 4; ++hf)
#pragma unroll
      for (int j = 0; j < 4; ++j) {
        const int rl = wr * 32 + mf * 16 + ((lane >> 4) << 2) + j;  // C/D: row=(l>>4)*4+j
        const int cl = wc * 64 + hf * 16 + (lane & 15);             //       col=l&15
        pt[rl * 128 + cl] = acc[mf][hf][j];
      }
#pragma unroll
  for (int p = 0; p < 4; ++p)
    atomicAdd(&ldsCnt[(t >> 4) + p * 16], cnt4[p]);
  __syncthreads();
  if (t < 64) cntp[kc * 512 + row_base + t] = (float)ldsCnt[t];
}

// ---------------------------------------------------------------------------
// Kernel 3: reduce partials over kc -> path_emb [512][128]
// ---------------------------------------------------------------------------
__global__ __launch_bounds__(128) void k_reduce(const float* __restrict__ part,
                                                const float* __restrict__ cntp,
                                                float* __restrict__ pe) {
  const int r = blockIdx.x;
  const int t = threadIdx.x;
  const int mt = r >> 6, rl = r & 63;
  const float* pp = part + (size_t)mt * 8192 + (size_t)rl * 128 + t;
  float s = 0.f;
#pragma unroll 6
  for (int kc = 0; kc < NKC; ++kc) s += pp[(size_t)kc * 8 * 8192];
  float c = 0.f;
#pragma unroll 6
  for (int kc = 0; kc < NKC; ++kc) c += cntp[kc * 512 + r];
  pe[r * HD + t] = (c > 0.f) ? (s / c) : 0.f;
}

// ---------------------------------------------------------------------------
// Kernel 4: mean over P, then LN -> FC1 -> ReLU -> BN -> LN -> FC2 -> ReLU -> BN
// One block per batch row b, 128 threads (t = h index).
// ---------------------------------------------------------------------------
__global__ __launch_bounds__(128) void k_tail(
    const float* __restrict__ pe,
    const float* __restrict__ w1, const float* __restrict__ b1,
    const float* __restrict__ w2, const float* __restrict__ b2,
    const float* __restrict__ ln1g, const float* __restrict__ ln1b,
    const float* __restrict__ ln2g, const float* __restrict__ ln2b,
    const float* __restrict__ bn1g, const float* __restrict__ bn1b,
    const float* __restrict__ bn2g, const float* __restrict__ bn2b,
    float* __restrict__ out) {
  const int b = blockIdx.x, t = threadIdx.x;
  __shared__ float sh[HD];
  __shared__ float red[HD];

  float x = 0.f;
#pragma unroll
  for (int p = 0; p < PD; ++p) x += pe[(b * PD + p) * HD + t];
  x *= (1.f / PD);

  const float bninv = rsqrtf(1.f + EPSF);

  // ---- LN1 ----
  red[t] = x; __syncthreads();
  for (int o = 64; o > 0; o >>= 1) { if (t < o) red[t] += red[t + o]; __syncthreads(); }
  const float mu1 = red[0] * (1.f / HD); __syncthreads();
  const float d1 = x - mu1;
  red[t] = d1 * d1; __syncthreads();
  for (int o = 64; o > 0; o >>= 1) { if (t < o) red[t] += red[t + o]; __syncthreads(); }
  const float v1 = red[0] * (1.f / HD); __syncthreads();
  const float y1 = ln1g[t] * d1 * rsqrtf(v1 + EPSF) + ln1b[t];

  // ---- FC1 + ReLU + BN1 ----
  sh[t] = y1; __syncthreads();
  float a = b1[t];
  const float4* wrow1 = (const float4*)(w1 + (size_t)t * HD);
#pragma unroll 8
  for (int k = 0; k < 32; ++k) {
    const float4 w = wrow1[k];
    a += w.x * sh[k * 4] + w.y * sh[k * 4 + 1] + w.z * sh[k * 4 + 2] + w.w * sh[k * 4 + 3];
  }
  a = fmaxf(a, 0.f);
  a = bn1g[t] * a * bninv + bn1b[t];
  __syncthreads();   // done with sh

  // ---- LN2 ----
  red[t] = a; __syncthreads();
  for (int o = 64; o > 0; o >>= 1) { if (t < o) red[t] += red[t + o]; __syncthreads(); }
  const float mu2 = red[0] * (1.f / HD); __syncthreads();
  const float d2 = a - mu2;
  red[t] = d2 * d2; __syncthreads();
  for (int o = 64; o > 0; o >>= 1) { if (t < o) red[t] += red[t + o]; __syncthreads(); }
  const float v2 = red[0] * (1.f / HD); __syncthreads();
  const float y2 = ln2g[t] * d2 * rsqrtf(v2 + EPSF) + ln2b[t];

  // ---- FC2 + ReLU + BN2 ----
  sh[t] = y2; __syncthreads();
  float a2 = b2[t];
  const float4* wrow2 = (const float4*)(w2 + (size_t)t * HD);
#pragma unroll 8
  for (int k = 0; k < 32; ++k) {
    const float4 w = wrow2[k];
    a2 += w.x * sh[k * 4] + w.y * sh[k * 4 + 1] + w.z * sh[k * 4 + 2] + w.w * sh[k * 4 + 3];
  }
  a2 = fmaxf(a2, 0.f);
  a2 = bn2g[t] * a2 * bninv + bn2b[t];
  out[b * HD + t] = a2;
}

// ---------------------------------------------------------------------------
extern "C" void kernel_launch(void* const* d_in, const int* in_sizes, int n_in,
                              void* d_out, int out_size, void* d_ws, size_t ws_size,
                              hipStream_t stream) {
  const int*   inp  = (const int*)d_in[0];
  const float* emb  = (const float*)d_in[1];
  const float* w1   = (const float*)d_in[2];
  const float* b1   = (const float*)d_in[3];
  const float* w2   = (const float*)d_in[4];
  const float* b2   = (const float*)d_in[5];
  const float* ln1g = (const float*)d_in[6];
  const float* ln1b = (const float*)d_in[7];
  const float* ln2g = (const float*)d_in[8];
  const float* ln2b = (const float*)d_in[9];
  const float* bn1g = (const float*)d_in[10];
  const float* bn1b = (const float*)d_in[11];
  const float* bn2g = (const float*)d_in[12];
  const float* bn2b = (const float*)d_in[13];
  float* out = (float*)d_out;

  // workspace layout
  char* ws = (char*)d_ws;
  uint16_t* embT = (uint16_t*)ws;                        // 50048*128*2 = 12,812,288 B
  float* part = (float*)(ws + 12812288);                 // 66*8*64*128*4 = 17,301,504 B
  float* cntp = (float*)(ws + 12812288 + 17301504);      // 66*512*4 = 135,168 B
  float* pe   = (float*)(ws + 12812288 + 17301504 + 135168); // 512*128*4 = 262,144 B

  k_embT<<<EP / 64, 256, 0, stream>>>(emb, embT);
  k_gemm<<<NKC * 8, 256, 0, stream>>>(inp, embT, part, cntp);
  k_reduce<<<MD, 128, 0, stream>>>(part, cntp, pe);
  k_tail<<<BD, 128, 0, stream>>>(pe, w1, b1, w2, b2, ln1g, ln1b, ln2g, ln2b,
                                 bn1g, bn1b, bn2g, bn2b, out);
}